// Round 18
// baseline (703.968 us; speedup 1.0000x reference)
//
#include <hip/hip_runtime.h>
#include <cmath>

#define D_MODEL 1024
#define D_STATE 16
#define D_INNER 2048
#define NB 4
#define SEQL 2048
#define ROWS (NB*SEQL)        // 8192
#define XZ_LD (2*D_INNER)     // 4096

typedef __attribute__((ext_vector_type(8))) short short8;
typedef __attribute__((ext_vector_type(4))) float f32x4;

__device__ __forceinline__ float sigmoidf_(float v) { return 1.0f / (1.0f + __expf(-v)); }

__device__ __forceinline__ unsigned short bf16rne(float f) {
    unsigned u = __float_as_uint(f);
    unsigned r = (u + 0x7FFFu + ((u >> 16) & 1u)) >> 16;
    return (unsigned short)r;
}

// ---------------- fp32 -> bf16 ----------------
__global__ __launch_bounds__(256) void pack1_k(const float4* __restrict__ in,
    ushort4* __restrict__ out, int n4)
{
    int i = blockIdx.x * 256 + threadIdx.x;
    if (i >= n4) return;
    float4 v = in[i];
    ushort4 h;
    h.x = bf16rne(v.x); h.y = bf16rne(v.y); h.z = bf16rne(v.z); h.w = bf16rne(v.w);
    out[i] = h;
}

// ============ 8-phase-style bf16 NT GEMM (round-10 schedule, verbatim) ============
#define GLDS(gp, lp) __builtin_amdgcn_global_load_lds( \
    (const __attribute__((address_space(1))) void*)(gp), \
    (__attribute__((address_space(3))) void*)(lp), 16, 0, 0)

extern __shared__ __align__(16) unsigned short smem8[];

template<int BM>
__global__ __launch_bounds__(512, 2) void gemm8p(
    const unsigned short* __restrict__ A2, int lda,
    const unsigned short* __restrict__ B2, int ldb,
    float* __restrict__ C, int ldc, int K)
{
    constexpr int APAN = BM * 32;
    constexpr int BPAN = 256 * 32;
    constexpr int LA   = BM / 128;
    constexpr int MH   = BM / 128;
    constexpr int WROW = (BM == 256) ? 128 : 64;
    unsigned short* sA = smem8;
    unsigned short* sB = smem8 + 3 * APAN;

    const int tid = threadIdx.x;
    const int bm = blockIdx.y * BM, bn = blockIdx.x * 256;
    const int wave = tid >> 6, lane = tid & 63;
    const int wm = wave >> 2, wn = wave & 3;
    const int fr = lane & 15, kq = lane >> 4;
    const int NT = K >> 5;

    size_t offA[LA], offB[2];
#pragma unroll
    for (int i = 0; i < LA; ++i) {
        int c = i * 512 + tid;
        int row = c & (BM - 1), slot = (BM == 256) ? (c >> 8) : (c >> 7);
        offA[i] = (size_t)(bm + row) * lda + slot * 8;
    }
#pragma unroll
    for (int i = 0; i < 2; ++i) {
        int c = i * 512 + tid;
        int row = c & 255, slot = c >> 8;
        offB[i] = (size_t)(bn + row) * ldb + slot * 8;
    }

    auto stageA = [&](int s) {
        int ka = s * 32;
        unsigned short* d = sA + (s % 3) * APAN;
#pragma unroll
        for (int i = 0; i < LA; ++i)
            GLDS(A2 + offA[i] + ka, d + (i * 512 + tid) * 8);
    };
    auto stageB = [&](int s) {
        int kb = s * 32;
        unsigned short* d = sB + (s % 3) * BPAN;
#pragma unroll
        for (int i = 0; i < 2; ++i)
            GLDS(B2 + offB[i] + kb, d + (i * 512 + tid) * 8);
    };

    f32x4 acc[4 * MH][4];
#pragma unroll
    for (int m = 0; m < 4 * MH; ++m)
#pragma unroll
        for (int n = 0; n < 4; ++n) acc[m][n] = (f32x4){0.f, 0.f, 0.f, 0.f};

    stageA(0); stageB(0); stageA(1); stageB(1);
    if constexpr (BM == 256) asm volatile("s_waitcnt vmcnt(4)" ::: "memory");
    else                     asm volatile("s_waitcnt vmcnt(3)" ::: "memory");
    __builtin_amdgcn_s_barrier();
    asm volatile("" ::: "memory");

    for (int t = 0; t < NT; ++t) {
        const unsigned short* pA = sA + (t % 3) * APAN;
        const unsigned short* pB = sB + (t % 3) * BPAN;
        short8 b0[4], a0[4];
#pragma unroll
        for (int n = 0; n < 4; ++n)
            b0[n] = *(const short8*)&pB[(kq * 256 + wn * 64 + n * 16 + fr) * 8];
#pragma unroll
        for (int m = 0; m < 4; ++m)
            a0[m] = *(const short8*)&pA[(kq * BM + wm * WROW + m * 16 + fr) * 8];
        if (t + 2 < NT) stageA(t + 2);
        if constexpr (MH == 1) { if (t + 2 < NT) stageB(t + 2); }
        __builtin_amdgcn_s_barrier();
        asm volatile("" ::: "memory");
        __builtin_amdgcn_s_setprio(1);
#pragma unroll
        for (int m = 0; m < 4; ++m)
#pragma unroll
            for (int n = 0; n < 4; ++n)
                acc[m][n] = __builtin_amdgcn_mfma_f32_16x16x32_bf16(a0[m], b0[n], acc[m][n], 0, 0, 0);
        __builtin_amdgcn_s_setprio(0);
        if constexpr (MH == 2) {
            __builtin_amdgcn_s_barrier();
            asm volatile("" ::: "memory");
            short8 a1[4];
#pragma unroll
            for (int m = 0; m < 4; ++m)
                a1[m] = *(const short8*)&pA[(kq * 256 + wm * 128 + 64 + m * 16 + fr) * 8];
            if (t + 2 < NT) stageB(t + 2);
            __builtin_amdgcn_s_barrier();
            asm volatile("" ::: "memory");
            __builtin_amdgcn_s_setprio(1);
#pragma unroll
            for (int m = 0; m < 4; ++m)
#pragma unroll
                for (int n = 0; n < 4; ++n)
                    acc[4 + m][n] = __builtin_amdgcn_mfma_f32_16x16x32_bf16(a1[m], b0[n], acc[4 + m][n], 0, 0, 0);
            __builtin_amdgcn_s_setprio(0);
        }
        if (t + 2 < NT) {
            if constexpr (BM == 256) asm volatile("s_waitcnt vmcnt(4)" ::: "memory");
            else                     asm volatile("s_waitcnt vmcnt(3)" ::: "memory");
        } else if (t + 1 < NT) {
            asm volatile("s_waitcnt vmcnt(0)" ::: "memory");
        }
        __builtin_amdgcn_s_barrier();
        asm volatile("" ::: "memory");
    }

    // C/D layout: col = lane&15, row = (lane>>4)*4 + j
#pragma unroll
    for (int mm = 0; mm < 4 * MH; ++mm) {
        int row0 = bm + wm * WROW + mm * 16 + kq * 4;
#pragma unroll
        for (int j = 0; j < 4; ++j) {
            float* Cr = C + (size_t)(row0 + j) * ldc + bn + wn * 64 + fr;
#pragma unroll
            for (int n = 0; n < 4; ++n) Cr[n * 16] = acc[mm][n][j];
        }
    }
}

// ---------------- causal depthwise conv (D_CONV=4) + SiLU ----------------
__global__ __launch_bounds__(256) void conv_silu_k(
    const float* __restrict__ xz, const float* __restrict__ conv_w,
    const float* __restrict__ conv_b, float* __restrict__ x_conv)
{
    int idx = blockIdx.x * 256 + threadIdx.x;   // ROWS * 512 total
    int q = idx & 511;
    int r = idx >> 9;
    int b = r >> 11, t = r & (SEQL - 1);
    int d0 = q << 2;
    float w[4][4];
#pragma unroll
    for (int c = 0; c < 4; ++c) *(float4*)w[c] = *(const float4*)&conv_w[(d0 + c) * 4];
    float4 acc = *(const float4*)&conv_b[d0];
    const float* xp = xz + (size_t)(b * SEQL) * XZ_LD + d0;
#pragma unroll
    for (int k = 0; k < 4; ++k) {
        int t2 = t - 3 + k;
        if (t2 >= 0) {
            float4 v = *(const float4*)(xp + (size_t)t2 * XZ_LD);
            acc.x = fmaf(v.x, w[0][k], acc.x);
            acc.y = fmaf(v.y, w[1][k], acc.y);
            acc.z = fmaf(v.z, w[2][k], acc.z);
            acc.w = fmaf(v.w, w[3][k], acc.w);
        }
    }
    acc.x *= sigmoidf_(acc.x);
    acc.y *= sigmoidf_(acc.y);
    acc.z *= sigmoidf_(acc.z);
    acc.w *= sigmoidf_(acc.w);
    *(float4*)&x_conv[(size_t)r * D_INNER + d0] = acc;
}

// ---- x_proj -> A_bar/B_bar/C, TRANSPOSED [b][s][t] (for the scan's per-lane reads) ----
__global__ __launch_bounds__(256) void proj_k(
    const float* __restrict__ x_conv, const float* __restrict__ W_xproj,
    const float* __restrict__ A_log,
    float* __restrict__ AbT, float* __restrict__ BbT, float* __restrict__ CbT)
{
    __shared__ float sdbl[4][33];
    int tid = threadIdx.x;
    int w = tid >> 6, lane = tid & 63;
    int row = blockIdx.x * 4 + w;
    const float* xrow = x_conv + (size_t)row * D_INNER;
    float4 xr[8];
#pragma unroll
    for (int it = 0; it < 8; ++it)
        xr[it] = *(const float4*)&xrow[it * 256 + lane * 4];

    for (int j = 0; j < 33; ++j) {
        const float* wrow = W_xproj + j * D_INNER;
        float accv = 0.f;
#pragma unroll
        for (int it = 0; it < 8; ++it) {
            float4 wv = *(const float4*)&wrow[it * 256 + lane * 4];
            accv = fmaf(xr[it].x, wv.x, accv);
            accv = fmaf(xr[it].y, wv.y, accv);
            accv = fmaf(xr[it].z, wv.z, accv);
            accv = fmaf(xr[it].w, wv.w, accv);
        }
#pragma unroll
        for (int off = 32; off; off >>= 1) accv += __shfl_xor(accv, off);
        if (lane == 0) sdbl[w][j] = accv;
    }
    __syncthreads();
    if (tid < 64) {
        int w2 = tid >> 4, s = tid & 15;
        int row2 = blockIdx.x * 4 + w2;
        int b2 = row2 >> 11, t2 = row2 & (SEQL - 1);
        size_t o = ((size_t)b2 * 16 + s) * SEQL + t2;
        float draw = sdbl[w2][32];
        float sp = (draw > 20.f) ? draw : log1pf(__expf(draw));
        float dt = fminf(fmaxf(sp, 0.001f), 0.1f);
        float Aa = -__expf(A_log[s]);
        float dtA = fminf(fmaxf(dt * Aa, -20.f), 0.f);
        AbT[o] = __expf(dtA);
        float bb = dt * sdbl[w2][s];
        BbT[o] = fminf(fmaxf(bb, -10.f), 10.f);
        CbT[o] = sdbl[w2][16 + s];
    }
}

// ---------------- SSM scan: 1 state per lane ----------------
// Params: register-prefetched global loads (transposed layout, L2-resident), issued one
// full chunk ahead (T14 issue-early; round-16's point-of-use loads were the failure mode).
// Phase B: round-14's sT LDS transpose (measured faster than shfl butterfly, r17).
// Staging buffers padded (round-14's 18.9M conflicts were the unpadded sXa[16][16]).
#define SCH 16
#define TT 16
#define NCH (SEQL / TT)
__global__ __launch_bounds__(256) void scan_k(
    const float* __restrict__ x_conv, const float* __restrict__ xz,
    unsigned short* __restrict__ yhl,
    const float* __restrict__ AbT, const float* __restrict__ BbT,
    const float* __restrict__ CbT, const float* __restrict__ D_param)
{
    __shared__ __align__(16) float sXa[2][SCH][20];   // [ch][t], 80B rows
    __shared__ float sZp[2][SCH][17];
    __shared__ __align__(16) float sT[SCH][328];      // [ch][t*20 + s], wave-private rows

    const int tid = threadIdx.x;
    const int b = blockIdx.y, dbase = blockIdx.x * SCH;
    const int chl = tid >> 4, s = tid & 15;
    const float* xc = x_conv + (size_t)(b * SEQL) * D_INNER + dbase;
    const float* zp = xz + (size_t)(b * SEQL) * XZ_LD + D_INNER + dbase;
    const float* pAg = AbT + ((size_t)b * 16 + s) * SEQL;
    const float* pBg = BbT + ((size_t)b * 16 + s) * SEQL;
    const float* pCg = CbT + ((size_t)b * 16 + s) * SEQL;
    const int st = tid >> 4, sc = tid & 15;   // staging: t = st, channel = sc (coalesced)

    auto stage = [&](int buf, int tc) {
        int t0 = tc * TT;
        sXa[buf][sc][st] = xc[(size_t)(t0 + st) * D_INNER + sc];
        sZp[buf][sc][st] = zp[(size_t)(t0 + st) * XZ_LD + sc];
    };

    // prefetch chunk 0 params into registers
    float4 fA[4], fB[4], fC[4];
#pragma unroll
    for (int q = 0; q < 4; ++q) {
        fA[q] = *(const float4*)&pAg[q * 4];
        fB[q] = *(const float4*)&pBg[q * 4];
        fC[q] = *(const float4*)&pCg[q * 4];
    }
    stage(0, 0);
    float h = 0.f;
    const float Dp = D_param[dbase + chl];

    for (int tc = 0; tc < NCH; ++tc) {
        int buf = tc & 1;
        int t0 = tc * TT;
        __syncthreads();
        if (tc + 1 < NCH) stage(buf ^ 1, tc + 1);

        // issue next chunk's param loads now; consumed next iteration (latency hidden)
        float4 gA[4], gB[4], gC[4];
        if (tc + 1 < NCH) {
            int t1 = t0 + TT;
#pragma unroll
            for (int q = 0; q < 4; ++q) {
                gA[q] = *(const float4*)&pAg[t1 + q * 4];
                gB[q] = *(const float4*)&pBg[t1 + q * 4];
                gC[q] = *(const float4*)&pCg[t1 + q * 4];
            }
        }

        // ---- phase A: h-recurrence; params already in registers ----
        float p[16];
#pragma unroll
        for (int q = 0; q < 4; ++q) {
            float4 a4 = fA[q], b4 = fB[q], c4 = fC[q];
            float4 x4 = *(const float4*)&sXa[buf][chl][q * 4];
            h = fminf(fmaxf(fmaf(b4.x, x4.x, a4.x * h), -100.f), 100.f); p[q * 4 + 0] = h * c4.x;
            h = fminf(fmaxf(fmaf(b4.y, x4.y, a4.y * h), -100.f), 100.f); p[q * 4 + 1] = h * c4.y;
            h = fminf(fmaxf(fmaf(b4.z, x4.z, a4.z * h), -100.f), 100.f); p[q * 4 + 2] = h * c4.z;
            h = fminf(fmaxf(fmaf(b4.w, x4.w, a4.w * h), -100.f), 100.f); p[q * 4 + 3] = h * c4.w;
        }

        // ---- phase B: wave-private sT transpose (2-way max, measured faster than shfl) ----
#pragma unroll
        for (int i = 0; i < 16; ++i) sT[chl][i * 20 + s] = p[i];
        float4 r0 = *(const float4*)&sT[chl][s * 20 + 0];
        float4 r1 = *(const float4*)&sT[chl][s * 20 + 4];
        float4 r2 = *(const float4*)&sT[chl][s * 20 + 8];
        float4 r3 = *(const float4*)&sT[chl][s * 20 + 12];
        float ysum = ((r0.x + r1.x + r2.x + r3.x) + (r0.y + r1.y + r2.y + r3.y))
                   + ((r0.z + r1.z + r2.z + r3.z) + (r0.w + r1.w + r2.w + r3.w));

        float z = sZp[buf][chl][s];
        float x = sXa[buf][chl][s];
        float o = fmaf(x, Dp, ysum * (z * sigmoidf_(z)));
        size_t r = (size_t)(b * SEQL + t0 + s);
        yhl[r * 2 * XZ_LD + dbase + chl] = bf16rne(o);

        // rotate prefetch registers
#pragma unroll
        for (int q = 0; q < 4; ++q) { fA[q] = gA[q]; fB[q] = gB[q]; fC[q] = gC[q]; }
    }
}

extern "C" void kernel_launch(void* const* d_in, const int* in_sizes, int n_in,
                              void* d_out, int out_size, void* d_ws, size_t ws_size,
                              hipStream_t stream) {
    const float* x       = (const float*)d_in[0];
    const float* W_in    = (const float*)d_in[1];
    const float* conv_w  = (const float*)d_in[2];
    const float* conv_b  = (const float*)d_in[3];
    const float* W_xproj = (const float*)d_in[4];
    const float* A_log   = (const float*)d_in[5];
    const float* D_param = (const float*)d_in[6];
    const float* W_out   = (const float*)d_in[7];
    float* out = (float*)d_out;

    // ---- workspace: round-1 footprint (202.9 MB), phase-aliased ----
    char* p = (char*)d_ws;
    char* xzB = p;
    float* xz = (float*)xzB;                 // 134.2 MB; rows: [x_proj | z] fp32
    p += (size_t)ROWS * XZ_LD * 4;
    char* xcB = p;
    float* x_conv = (float*)xcB;             // 67.1 MB
    p += (size_t)ROWS * D_INNER * 4;
    float* AbT = (float*)p; p += (size_t)ROWS * 16 * 4;   // [b][s][t], 512 KB each
    float* BbT = (float*)p; p += (size_t)ROWS * 16 * 4;
    float* CbT = (float*)p; p += (size_t)ROWS * 16 * 4;

    // phase-0 aliases in x_conv region: x1 (8192x1024) + Wi1 (4096x1024) bf16 = 25.2 MB
    unsigned short* x1  = (unsigned short*)xcB;
    unsigned short* Wi1 = x1 + (size_t)ROWS * D_MODEL;
    // phase-4 alias in x_conv region (after scan consumed x_conv): Wo1 (1024x2048) = 4.2 MB
    unsigned short* Wo1 = (unsigned short*)xcB;
    // scan writes yh into the x_proj half of xz rows (pitch 2*XZ_LD ushorts)
    unsigned short* yhl = (unsigned short*)xzB;

    constexpr int SM1 = (3 * 256 * 32 + 3 * 256 * 32) * 2;   // 96 KiB
    constexpr int SM2 = (3 * 128 * 32 + 3 * 256 * 32) * 2;   // 72 KiB

    // 0) pack x, W_in -> bf16
    pack1_k<<<ROWS * D_MODEL / 4 / 256, 256, 0, stream>>>(
        (const float4*)x, (ushort4*)x1, ROWS * D_MODEL / 4);
    pack1_k<<<2 * D_INNER * D_MODEL / 4 / 256, 256, 0, stream>>>(
        (const float4*)W_in, (ushort4*)Wi1, 2 * D_INNER * D_MODEL / 4);
    // 1) xz = x @ W_in^T  (M=8192, N=4096, K=1024)
    gemm8p<256><<<dim3(4096 / 256, ROWS / 256), 512, SM1, stream>>>(
        x1, D_MODEL, Wi1, D_MODEL, xz, XZ_LD, D_MODEL);
    // 2) conv + silu
    conv_silu_k<<<ROWS * 512 / 256, 256, 0, stream>>>(xz, conv_w, conv_b, x_conv);
    // 3) x_proj -> transposed A_bar/B_bar/C
    proj_k<<<ROWS / 4, 256, 0, stream>>>(x_conv, W_xproj, A_log, AbT, BbT, CbT);
    // 4) scan -> yh bf16 into xz rows' first half
    scan_k<<<dim3(D_INNER / SCH, NB), 256, 0, stream>>>(
        x_conv, xz, yhl, AbT, BbT, CbT, D_param);
    // 5) pack W_out -> bf16 into the now-dead x_conv region
    pack1_k<<<D_MODEL * D_INNER / 4 / 256, 256, 0, stream>>>(
        (const float4*)W_out, (ushort4*)Wo1, D_MODEL * D_INNER / 4);
    // 6) out = y @ W_out^T  (M=8192, N=1024, K=2048); A = yh (pitch 2*XZ_LD), B pitch D_INNER
    gemm8p<128><<<dim3(1024 / 256, ROWS / 128), 512, SM2, stream>>>(
        yhl, 2 * XZ_LD, Wo1, D_INNER, out, D_MODEL, D_INNER);
}

// Round 19
// 488.002 us; speedup vs baseline: 1.4426x; 1.4426x over previous
//
#include <hip/hip_runtime.h>
#include <cmath>

#define D_MODEL 1024
#define D_STATE 16
#define D_INNER 2048
#define NB 4
#define SEQL 2048
#define ROWS (NB*SEQL)        // 8192
#define XZ_LD (2*D_INNER)     // 4096

typedef __attribute__((ext_vector_type(8))) short short8;
typedef __attribute__((ext_vector_type(4))) float f32x4;

__device__ __forceinline__ float sigmoidf_(float v) { return 1.0f / (1.0f + __expf(-v)); }

__device__ __forceinline__ unsigned short bf16rne(float f) {
    unsigned u = __float_as_uint(f);
    unsigned r = (u + 0x7FFFu + ((u >> 16) & 1u)) >> 16;
    return (unsigned short)r;
}

// ---------------- fp32 -> bf16 ----------------
__global__ __launch_bounds__(256) void pack1_k(const float4* __restrict__ in,
    ushort4* __restrict__ out, int n4)
{
    int i = blockIdx.x * 256 + threadIdx.x;
    if (i >= n4) return;
    float4 v = in[i];
    ushort4 h;
    h.x = bf16rne(v.x); h.y = bf16rne(v.y); h.z = bf16rne(v.z); h.w = bf16rne(v.w);
    out[i] = h;
}

// ============ 8-phase-style bf16 NT GEMM (round-10 schedule, verbatim) ============
#define GLDS(gp, lp) __builtin_amdgcn_global_load_lds( \
    (const __attribute__((address_space(1))) void*)(gp), \
    (__attribute__((address_space(3))) void*)(lp), 16, 0, 0)

extern __shared__ __align__(16) unsigned short smem8[];

template<int BM>
__global__ __launch_bounds__(512, 2) void gemm8p(
    const unsigned short* __restrict__ A2, int lda,
    const unsigned short* __restrict__ B2, int ldb,
    float* __restrict__ C, int ldc, int K)
{
    constexpr int APAN = BM * 32;
    constexpr int BPAN = 256 * 32;
    constexpr int LA   = BM / 128;
    constexpr int MH   = BM / 128;
    constexpr int WROW = (BM == 256) ? 128 : 64;
    unsigned short* sA = smem8;
    unsigned short* sB = smem8 + 3 * APAN;

    const int tid = threadIdx.x;
    const int bm = blockIdx.y * BM, bn = blockIdx.x * 256;
    const int wave = tid >> 6, lane = tid & 63;
    const int wm = wave >> 2, wn = wave & 3;
    const int fr = lane & 15, kq = lane >> 4;
    const int NT = K >> 5;

    size_t offA[LA], offB[2];
#pragma unroll
    for (int i = 0; i < LA; ++i) {
        int c = i * 512 + tid;
        int row = c & (BM - 1), slot = (BM == 256) ? (c >> 8) : (c >> 7);
        offA[i] = (size_t)(bm + row) * lda + slot * 8;
    }
#pragma unroll
    for (int i = 0; i < 2; ++i) {
        int c = i * 512 + tid;
        int row = c & 255, slot = c >> 8;
        offB[i] = (size_t)(bn + row) * ldb + slot * 8;
    }

    auto stageA = [&](int s) {
        int ka = s * 32;
        unsigned short* d = sA + (s % 3) * APAN;
#pragma unroll
        for (int i = 0; i < LA; ++i)
            GLDS(A2 + offA[i] + ka, d + (i * 512 + tid) * 8);
    };
    auto stageB = [&](int s) {
        int kb = s * 32;
        unsigned short* d = sB + (s % 3) * BPAN;
#pragma unroll
        for (int i = 0; i < 2; ++i)
            GLDS(B2 + offB[i] + kb, d + (i * 512 + tid) * 8);
    };

    f32x4 acc[4 * MH][4];
#pragma unroll
    for (int m = 0; m < 4 * MH; ++m)
#pragma unroll
        for (int n = 0; n < 4; ++n) acc[m][n] = (f32x4){0.f, 0.f, 0.f, 0.f};

    stageA(0); stageB(0); stageA(1); stageB(1);
    if constexpr (BM == 256) asm volatile("s_waitcnt vmcnt(4)" ::: "memory");
    else                     asm volatile("s_waitcnt vmcnt(3)" ::: "memory");
    __builtin_amdgcn_s_barrier();
    asm volatile("" ::: "memory");

    for (int t = 0; t < NT; ++t) {
        const unsigned short* pA = sA + (t % 3) * APAN;
        const unsigned short* pB = sB + (t % 3) * BPAN;
        short8 b0[4], a0[4];
#pragma unroll
        for (int n = 0; n < 4; ++n)
            b0[n] = *(const short8*)&pB[(kq * 256 + wn * 64 + n * 16 + fr) * 8];
#pragma unroll
        for (int m = 0; m < 4; ++m)
            a0[m] = *(const short8*)&pA[(kq * BM + wm * WROW + m * 16 + fr) * 8];
        if (t + 2 < NT) stageA(t + 2);
        if constexpr (MH == 1) { if (t + 2 < NT) stageB(t + 2); }
        __builtin_amdgcn_s_barrier();
        asm volatile("" ::: "memory");
        __builtin_amdgcn_s_setprio(1);
#pragma unroll
        for (int m = 0; m < 4; ++m)
#pragma unroll
            for (int n = 0; n < 4; ++n)
                acc[m][n] = __builtin_amdgcn_mfma_f32_16x16x32_bf16(a0[m], b0[n], acc[m][n], 0, 0, 0);
        __builtin_amdgcn_s_setprio(0);
        if constexpr (MH == 2) {
            __builtin_amdgcn_s_barrier();
            asm volatile("" ::: "memory");
            short8 a1[4];
#pragma unroll
            for (int m = 0; m < 4; ++m)
                a1[m] = *(const short8*)&pA[(kq * 256 + wm * 128 + 64 + m * 16 + fr) * 8];
            if (t + 2 < NT) stageB(t + 2);
            __builtin_amdgcn_s_barrier();
            asm volatile("" ::: "memory");
            __builtin_amdgcn_s_setprio(1);
#pragma unroll
            for (int m = 0; m < 4; ++m)
#pragma unroll
                for (int n = 0; n < 4; ++n)
                    acc[4 + m][n] = __builtin_amdgcn_mfma_f32_16x16x32_bf16(a1[m], b0[n], acc[4 + m][n], 0, 0, 0);
            __builtin_amdgcn_s_setprio(0);
        }
        if (t + 2 < NT) {
            if constexpr (BM == 256) asm volatile("s_waitcnt vmcnt(4)" ::: "memory");
            else                     asm volatile("s_waitcnt vmcnt(3)" ::: "memory");
        } else if (t + 1 < NT) {
            asm volatile("s_waitcnt vmcnt(0)" ::: "memory");
        }
        __builtin_amdgcn_s_barrier();
        asm volatile("" ::: "memory");
    }

    // C/D layout: col = lane&15, row = (lane>>4)*4 + j
#pragma unroll
    for (int mm = 0; mm < 4 * MH; ++mm) {
        int row0 = bm + wm * WROW + mm * 16 + kq * 4;
#pragma unroll
        for (int j = 0; j < 4; ++j) {
            float* Cr = C + (size_t)(row0 + j) * ldc + bn + wn * 64 + fr;
#pragma unroll
            for (int n = 0; n < 4; ++n) Cr[n * 16] = acc[mm][n][j];
        }
    }
}

// ---------------- causal depthwise conv (D_CONV=4) + SiLU ----------------
__global__ __launch_bounds__(256) void conv_silu_k(
    const float* __restrict__ xz, const float* __restrict__ conv_w,
    const float* __restrict__ conv_b, float* __restrict__ x_conv)
{
    int idx = blockIdx.x * 256 + threadIdx.x;   // ROWS * 512 total
    int q = idx & 511;
    int r = idx >> 9;
    int b = r >> 11, t = r & (SEQL - 1);
    int d0 = q << 2;
    float w[4][4];
#pragma unroll
    for (int c = 0; c < 4; ++c) *(float4*)w[c] = *(const float4*)&conv_w[(d0 + c) * 4];
    float4 acc = *(const float4*)&conv_b[d0];
    const float* xp = xz + (size_t)(b * SEQL) * XZ_LD + d0;
#pragma unroll
    for (int k = 0; k < 4; ++k) {
        int t2 = t - 3 + k;
        if (t2 >= 0) {
            float4 v = *(const float4*)(xp + (size_t)t2 * XZ_LD);
            acc.x = fmaf(v.x, w[0][k], acc.x);
            acc.y = fmaf(v.y, w[1][k], acc.y);
            acc.z = fmaf(v.z, w[2][k], acc.z);
            acc.w = fmaf(v.w, w[3][k], acc.w);
        }
    }
    acc.x *= sigmoidf_(acc.x);
    acc.y *= sigmoidf_(acc.y);
    acc.z *= sigmoidf_(acc.z);
    acc.w *= sigmoidf_(acc.w);
    *(float4*)&x_conv[(size_t)r * D_INNER + d0] = acc;
}

// ---- x_proj -> A_bar/B_bar/C, normal [row][s] layout (coalesced scan staging) ----
__global__ __launch_bounds__(256) void proj_k(
    const float* __restrict__ x_conv, const float* __restrict__ W_xproj,
    const float* __restrict__ A_log,
    float* __restrict__ Abar, float* __restrict__ Bbar, float* __restrict__ Cmat)
{
    __shared__ float sdbl[4][33];
    int tid = threadIdx.x;
    int w = tid >> 6, lane = tid & 63;
    int row = blockIdx.x * 4 + w;
    const float* xrow = x_conv + (size_t)row * D_INNER;
    float4 xr[8];
#pragma unroll
    for (int it = 0; it < 8; ++it)
        xr[it] = *(const float4*)&xrow[it * 256 + lane * 4];

    for (int j = 0; j < 33; ++j) {
        const float* wrow = W_xproj + j * D_INNER;
        float accv = 0.f;
#pragma unroll
        for (int it = 0; it < 8; ++it) {
            float4 wv = *(const float4*)&wrow[it * 256 + lane * 4];
            accv = fmaf(xr[it].x, wv.x, accv);
            accv = fmaf(xr[it].y, wv.y, accv);
            accv = fmaf(xr[it].z, wv.z, accv);
            accv = fmaf(xr[it].w, wv.w, accv);
        }
#pragma unroll
        for (int off = 32; off; off >>= 1) accv += __shfl_xor(accv, off);
        if (lane == 0) sdbl[w][j] = accv;
    }
    __syncthreads();
    if (tid < 64) {
        int w2 = tid >> 4, s = tid & 15;
        int row2 = blockIdx.x * 4 + w2;
        float draw = sdbl[w2][32];
        float sp = (draw > 20.f) ? draw : log1pf(__expf(draw));
        float dt = fminf(fmaxf(sp, 0.001f), 0.1f);
        float Aa = -__expf(A_log[s]);
        float dtA = fminf(fmaxf(dt * Aa, -20.f), 0.f);
        Abar[row2 * 16 + s] = __expf(dtA);
        float bb = dt * sdbl[w2][s];
        Bbar[row2 * 16 + s] = fminf(fmaxf(bb, -10.f), 10.f);
        Cmat[row2 * 16 + s] = sdbl[w2][16 + s];
    }
}

// ---------------- SSM scan: round-14 structure (measured 153 us) with the sXa
// padding fix (write conflicts 8-way -> 2-way) and the yl write dropped ----------------
#define SCH 16
#define TT 16
__global__ __launch_bounds__(256) void scan_k(
    const float* __restrict__ x_conv, const float* __restrict__ xz,
    unsigned short* __restrict__ yhl,
    const float* __restrict__ Abar, const float* __restrict__ Bbar,
    const float* __restrict__ Cmat, const float* __restrict__ D_param)
{
    __shared__ __align__(16) float sXa[2][SCH][20];    // [ch][t], pad 20 (r14 was 16: 8-way)
    __shared__ float sZp[2][SCH][17];
    __shared__ __align__(16) float sPa[2][16][20];     // [s][t], pad 20 (2-way)
    __shared__ __align__(16) float sPb[2][16][20];
    __shared__ __align__(16) float sPc[2][16][20];
    __shared__ __align__(16) float sT[SCH][328];       // [ch][t*20 + s]

    const int tid = threadIdx.x;
    const int b = blockIdx.y, dbase = blockIdx.x * SCH;
    const int chl = tid >> 4, s = tid & 15;
    const float* xc = x_conv + (size_t)(b * SEQL) * D_INNER + dbase;
    const float* zp = xz + (size_t)(b * SEQL) * XZ_LD + D_INNER + dbase;
    const int pbase0 = (b * SEQL) * 16;
    const int st = tid >> 4, sc = tid & 15;   // staging: t = st, channel/state = sc

    auto stage = [&](int buf, int tc) {
        int t0 = tc * TT;
        sXa[buf][sc][st] = xc[(size_t)(t0 + st) * D_INNER + sc];
        sZp[buf][sc][st] = zp[(size_t)(t0 + st) * XZ_LD + sc];
        int g = pbase0 + t0 * 16 + tid;       // coalesced: t = tid>>4, s = tid&15
        sPa[buf][sc][st] = Abar[g];
        sPb[buf][sc][st] = Bbar[g];
        sPc[buf][sc][st] = Cmat[g];
    };

    stage(0, 0);
    float h = 0.f;
    const float Dp = D_param[dbase + chl];

    for (int tc = 0; tc < SEQL / TT; ++tc) {
        int buf = tc & 1;
        int t0 = tc * TT;
        __syncthreads();
        if (tc + 1 < SEQL / TT) stage(buf ^ 1, tc + 1);

        // ---- phase A: h-recurrence; params + x from LDS (prefetched last chunk) ----
        float p[16];
#pragma unroll
        for (int q = 0; q < 4; ++q) {
            float4 a4 = *(const float4*)&sPa[buf][s][q * 4];
            float4 b4 = *(const float4*)&sPb[buf][s][q * 4];
            float4 c4 = *(const float4*)&sPc[buf][s][q * 4];
            float4 x4 = *(const float4*)&sXa[buf][chl][q * 4];
            h = fminf(fmaxf(fmaf(b4.x, x4.x, a4.x * h), -100.f), 100.f); p[q * 4 + 0] = h * c4.x;
            h = fminf(fmaxf(fmaf(b4.y, x4.y, a4.y * h), -100.f), 100.f); p[q * 4 + 1] = h * c4.y;
            h = fminf(fmaxf(fmaf(b4.z, x4.z, a4.z * h), -100.f), 100.f); p[q * 4 + 2] = h * c4.z;
            h = fminf(fmaxf(fmaf(b4.w, x4.w, a4.w * h), -100.f), 100.f); p[q * 4 + 3] = h * c4.w;
        }

        // ---- phase B: wave-private sT transpose (r14 structure, measured faster) ----
#pragma unroll
        for (int i = 0; i < 16; ++i) sT[chl][i * 20 + s] = p[i];
        float4 r0 = *(const float4*)&sT[chl][s * 20 + 0];
        float4 r1 = *(const float4*)&sT[chl][s * 20 + 4];
        float4 r2 = *(const float4*)&sT[chl][s * 20 + 8];
        float4 r3 = *(const float4*)&sT[chl][s * 20 + 12];
        float ysum = ((r0.x + r1.x + r2.x + r3.x) + (r0.y + r1.y + r2.y + r3.y))
                   + ((r0.z + r1.z + r2.z + r3.z) + (r0.w + r1.w + r2.w + r3.w));

        float z = sZp[buf][chl][s];
        float x = sXa[buf][chl][s];
        float o = fmaf(x, Dp, ysum * (z * sigmoidf_(z)));
        size_t r = (size_t)(b * SEQL + t0 + s);
        yhl[r * 2 * XZ_LD + dbase + chl] = bf16rne(o);
    }
}

extern "C" void kernel_launch(void* const* d_in, const int* in_sizes, int n_in,
                              void* d_out, int out_size, void* d_ws, size_t ws_size,
                              hipStream_t stream) {
    const float* x       = (const float*)d_in[0];
    const float* W_in    = (const float*)d_in[1];
    const float* conv_w  = (const float*)d_in[2];
    const float* conv_b  = (const float*)d_in[3];
    const float* W_xproj = (const float*)d_in[4];
    const float* A_log   = (const float*)d_in[5];
    const float* D_param = (const float*)d_in[6];
    const float* W_out   = (const float*)d_in[7];
    float* out = (float*)d_out;

    // ---- workspace: round-1 footprint (202.9 MB), phase-aliased ----
    char* p = (char*)d_ws;
    char* xzB = p;
    float* xz = (float*)xzB;                 // 134.2 MB; rows: [x_proj | z] fp32
    p += (size_t)ROWS * XZ_LD * 4;
    char* xcB = p;
    float* x_conv = (float*)xcB;             // 67.1 MB
    p += (size_t)ROWS * D_INNER * 4;
    float* Abar = (float*)p; p += (size_t)ROWS * 16 * 4;
    float* Bbar = (float*)p; p += (size_t)ROWS * 16 * 4;
    float* Cm   = (float*)p; p += (size_t)ROWS * 16 * 4;

    // phase-0 aliases in x_conv region: x1 (8192x1024) + Wi1 (4096x1024) bf16 = 25.2 MB
    unsigned short* x1  = (unsigned short*)xcB;
    unsigned short* Wi1 = x1 + (size_t)ROWS * D_MODEL;
    // phase-4 alias in x_conv region (after scan consumed x_conv): Wo1 (1024x2048) = 4.2 MB
    unsigned short* Wo1 = (unsigned short*)xcB;
    // scan writes yh into the x_proj half of xz rows (pitch 2*XZ_LD ushorts)
    unsigned short* yhl = (unsigned short*)xzB;

    constexpr int SM1 = (3 * 256 * 32 + 3 * 256 * 32) * 2;   // 96 KiB
    constexpr int SM2 = (3 * 128 * 32 + 3 * 256 * 32) * 2;   // 72 KiB

    // 0) pack x, W_in -> bf16
    pack1_k<<<ROWS * D_MODEL / 4 / 256, 256, 0, stream>>>(
        (const float4*)x, (ushort4*)x1, ROWS * D_MODEL / 4);
    pack1_k<<<2 * D_INNER * D_MODEL / 4 / 256, 256, 0, stream>>>(
        (const float4*)W_in, (ushort4*)Wi1, 2 * D_INNER * D_MODEL / 4);
    // 1) xz = x @ W_in^T  (M=8192, N=4096, K=1024)
    gemm8p<256><<<dim3(4096 / 256, ROWS / 256), 512, SM1, stream>>>(
        x1, D_MODEL, Wi1, D_MODEL, xz, XZ_LD, D_MODEL);
    // 2) conv + silu
    conv_silu_k<<<ROWS * 512 / 256, 256, 0, stream>>>(xz, conv_w, conv_b, x_conv);
    // 3) x_proj -> A_bar/B_bar/C (normal layout)
    proj_k<<<ROWS / 4, 256, 0, stream>>>(x_conv, W_xproj, A_log, Abar, Bbar, Cm);
    // 4) scan -> yh bf16 into xz rows' first half
    scan_k<<<dim3(D_INNER / SCH, NB), 256, 0, stream>>>(
        x_conv, xz, yhl, Abar, Bbar, Cm, D_param);
    // 5) pack W_out -> bf16 into the now-dead x_conv region
    pack1_k<<<D_MODEL * D_INNER / 4 / 256, 256, 0, stream>>>(
        (const float4*)W_out, (ushort4*)Wo1, D_MODEL * D_INNER / 4);
    // 6) out = y @ W_out^T  (M=8192, N=1024, K=2048); A = yh (pitch 2*XZ_LD), B pitch D_INNER
    gemm8p<128><<<dim3(1024 / 256, ROWS / 128), 512, SM2, stream>>>(
        yhl, 2 * XZ_LD, Wo1, D_INNER, out, D_MODEL, D_INNER);
}